// Round 4
// baseline (1157.028 us; speedup 1.0000x reference)
//
#include <hip/hip_runtime.h>
#include <hip/hip_bf16.h>

#define HIDDEN   2880
#define INTER    2880
#define NEXP     8
#define GUP_ROWS (2*INTER)   // 5760
#define NPAIR    2048

#define NK   (HIDDEN/32)     // 90 k-tiles of 32
#define BM   256             // rows per block (2 row-groups x 128)
#define BN1  128             // gemm1 cols per block (4 col-groups x 32)
#define BN2  64              // gemm2 cols per block (4 col-groups x 16)
#define MT_MAX 3             // 768 rows/expert capacity (n_e ~ 256 +/- 15)

#define UBYTES ((size_t)NPAIR * INTER * 2)    // u bf16
#define ABYTES ((size_t)NPAIR * HIDDEN * 2)   // gathered A bf16

using bf16x8 = __attribute__((ext_vector_type(8))) short;
using f32x4  = __attribute__((ext_vector_type(4))) float;

__device__ __forceinline__ unsigned cvt2bf(float a, float b) {
  union { __hip_bfloat16 h; unsigned short s; } x, y;
  x.h = __float2bfloat16(a);
  y.h = __float2bfloat16(b);
  return (unsigned)x.s | ((unsigned)y.s << 16);
}

__device__ __forceinline__ bf16x8 cvt8(const float4& lo, const float4& hi) {
  union { bf16x8 v; unsigned u[4]; } r;
  r.u[0] = cvt2bf(lo.x, lo.y);
  r.u[1] = cvt2bf(lo.z, lo.w);
  r.u[2] = cvt2bf(hi.x, hi.y);
  r.u[3] = cvt2bf(hi.z, hi.w);
  return r.v;
}

// ---------------- routing ----------------
// meta: [0..7]=counts  [8..15]=offsets  [16..23]=cursor
__global__ void route_count(const int* __restrict__ eidx, int* __restrict__ meta) {
  __shared__ int cnt[NEXP];
  int t = threadIdx.x;
  if (t < NEXP) cnt[t] = 0;
  __syncthreads();
  for (int a = t; a < NPAIR; a += 256) atomicAdd(&cnt[eidx[a]], 1);
  __syncthreads();
  if (t == 0) {
    int off = 0;
    for (int e = 0; e < NEXP; ++e) {
      meta[e] = cnt[e];
      meta[8 + e] = off;
      meta[16 + e] = off;
      off += cnt[e];
    }
  }
}

__global__ void route_scatter(const int* __restrict__ eidx, int* __restrict__ meta,
                              int* __restrict__ list) {
  int a = blockIdx.x * 256 + threadIdx.x;
  int e = eidx[a];
  int pos = atomicAdd(&meta[16 + e], 1);
  list[pos] = a;   // a = token*4 + slot
}

// ---------------- gather A rows to bf16, expert-sorted ----------------
__global__ void gather_a(const float* __restrict__ t, const int* __restrict__ list,
                         __hip_bfloat16* __restrict__ abuf) {
  int i = blockIdx.x;
  int tok = list[i] >> 2;
  const float* src = t + (size_t)tok * HIDDEN;
  char* dst = (char*)(abuf + (size_t)i * HIDDEN);
  for (int c = threadIdx.x * 4; c < HIDDEN; c += 256 * 4) {
    float4 v = *(const float4*)(src + c);
    uint2 w; w.x = cvt2bf(v.x, v.y); w.y = cvt2bf(v.z, v.w);
    *(uint2*)(dst + (size_t)c * 2) = w;
  }
}

// ---------------- GEMM1: LDS-free, fragment-direct loads ----------------
// 8 waves: wr = wave>>2 (row half), wn = wave&3 (col group of 32)
__global__ __launch_bounds__(512)
void gemm1_swiglu(const __hip_bfloat16* __restrict__ abuf,
                  const float* __restrict__ gup,
                  const float* __restrict__ gub,
                  const int* __restrict__ meta,
                  __hip_bfloat16* __restrict__ u)
{
  const int e = blockIdx.z, mt = blockIdx.y, nt = blockIdx.x;
  const int n_e = meta[e];
  const int m0 = mt * BM;
  if (m0 >= n_e) return;
  const int base = meta[8 + e];

  const int tid = threadIdx.x, lane = tid & 63, wid = tid >> 6;
  const int wr = wid >> 2, wn = wid & 3;
  const int kq = lane >> 4;          // k-quarter 0..3 (8 elems each)

  // A fragment pointers: row = m0 + wr*128 + fm*16 + (lane&15), 16B per k-tile slot
  const char* aPtr[8];
  #pragma unroll
  for (int fm = 0; fm < 8; ++fm) {
    int rl = m0 + wr * 128 + fm * 16 + (lane & 15);
    int rc = (rl < n_e) ? rl : 0;
    aPtr[fm] = (const char*)(abuf + (size_t)(base + rc) * HIDDEN) + kq * 16;
  }
  // B fragment pointers: col = nt*128 + wn*32 + fn*16 + (lane&15), 32B f32 per k-tile slot
  const char* bPtr[2];
  #pragma unroll
  for (int fn = 0; fn < 2; ++fn) {
    int col = nt * BN1 + wn * 32 + fn * 16 + (lane & 15);
    bPtr[fn] = (const char*)(gup + (size_t)(e * GUP_ROWS + col) * HIDDEN) + kq * 32;
  }

  f32x4 acc[8][2];
  #pragma unroll
  for (int fm = 0; fm < 8; ++fm)
    #pragma unroll
    for (int fn = 0; fn < 2; ++fn)
      acc[fm][fn] = f32x4{0.f, 0.f, 0.f, 0.f};

  bf16x8 aA[8], aB[8];
  float4 rbA[2][2], rbB[2][2];

#define LA1(kt, dst) { _Pragma("unroll") for (int fm = 0; fm < 8; ++fm) \
    dst[fm] = *(const bf16x8*)(aPtr[fm] + (size_t)(kt) * 64); }
#define LB1(kt, dst) { _Pragma("unroll") for (int fn = 0; fn < 2; ++fn) { \
    dst[fn][0] = *(const float4*)(bPtr[fn] + (size_t)(kt) * 128); \
    dst[fn][1] = *(const float4*)(bPtr[fn] + (size_t)(kt) * 128 + 16); } }
#define COMP1(a, rb) { bf16x8 bb[2]; \
    _Pragma("unroll") for (int fn = 0; fn < 2; ++fn) bb[fn] = cvt8(rb[fn][0], rb[fn][1]); \
    _Pragma("unroll") for (int fm = 0; fm < 8; ++fm) \
      _Pragma("unroll") for (int fn = 0; fn < 2; ++fn) \
        acc[fm][fn] = __builtin_amdgcn_mfma_f32_16x16x32_bf16(a[fm], bb[fn], acc[fm][fn], 0, 0, 0); }

  LA1(0, aA); LB1(0, rbA);
  LA1(1, aB); LB1(1, rbB);
  for (int kt = 0; kt < NK; kt += 2) {
    COMP1(aA, rbA);
    if (kt + 2 < NK) { LA1(kt + 2, aA); LB1(kt + 2, rbA); }
    COMP1(aB, rbB);
    if (kt + 3 < NK) { LA1(kt + 3, aB); LB1(kt + 3, rbB); }
  }

  // epilogue: +bias, swiglu (even col = glu, odd = lin), write u bf16
  const int colBase = nt * BN1 + wn * 32 + (lane & 15);
  const int rowBase = m0 + wr * 128 + ((lane >> 4) * 4);
  #pragma unroll
  for (int fm = 0; fm < 8; ++fm) {
    #pragma unroll
    for (int fn = 0; fn < 2; ++fn) {
      const int colg = colBase + fn * 16;
      const float bias = gub[e * GUP_ROWS + colg];
      #pragma unroll
      for (int j = 0; j < 4; ++j) {
        float h = acc[fm][fn][j] + bias;
        float other = __shfl_xor(h, 1, 64);
        int row = rowBase + fm * 16 + j;
        if (!(lane & 1)) {
          float xg = fminf(h, 7.0f);
          float xl = fminf(fmaxf(other, -7.0f), 7.0f);
          float og = xg / (1.0f + __expf(-1.702f * xg));
          float uv = og * (xl + 1.0f);
          if (row < n_e)
            u[(size_t)(base + row) * INTER + (colg >> 1)] = __float2bfloat16(uv);
        }
      }
    }
  }
}

// ---------------- GEMM2: LDS-free, scatter output ----------------
__global__ __launch_bounds__(512)
void gemm2_down(const __hip_bfloat16* __restrict__ u,
                const float* __restrict__ dwn,
                const float* __restrict__ dbias,
                const int* __restrict__ meta,
                const int* __restrict__ list,
                float* __restrict__ out)
{
  const int e = blockIdx.z, mt = blockIdx.y, nt = blockIdx.x;
  const int n_e = meta[e];
  const int m0 = mt * BM;
  if (m0 >= n_e) return;
  const int base = meta[8 + e];

  const int tid = threadIdx.x, lane = tid & 63, wid = tid >> 6;
  const int wr = wid >> 2, wn = wid & 3;
  const int kq = lane >> 4;

  const char* aPtr[8];
  #pragma unroll
  for (int fm = 0; fm < 8; ++fm) {
    int rl = m0 + wr * 128 + fm * 16 + (lane & 15);
    int rc = (rl < n_e) ? rl : 0;
    aPtr[fm] = (const char*)(u + (size_t)(base + rc) * INTER) + kq * 16;
  }
  const int col = nt * BN2 + wn * 16 + (lane & 15);
  const char* bPtr = (const char*)(dwn + ((size_t)e * HIDDEN + col) * INTER) + kq * 32;

  f32x4 acc[8];
  #pragma unroll
  for (int fm = 0; fm < 8; ++fm) acc[fm] = f32x4{0.f, 0.f, 0.f, 0.f};

  bf16x8 aA[8], aB[8];
  float4 rbA[2], rbB[2];

#define LA2(kt, dst) { _Pragma("unroll") for (int fm = 0; fm < 8; ++fm) \
    dst[fm] = *(const bf16x8*)(aPtr[fm] + (size_t)(kt) * 64); }
#define LB2(kt, dst) { \
    dst[0] = *(const float4*)(bPtr + (size_t)(kt) * 128); \
    dst[1] = *(const float4*)(bPtr + (size_t)(kt) * 128 + 16); }
#define COMP2(a, rb) { bf16x8 bb = cvt8(rb[0], rb[1]); \
    _Pragma("unroll") for (int fm = 0; fm < 8; ++fm) \
      acc[fm] = __builtin_amdgcn_mfma_f32_16x16x32_bf16(a[fm], bb, acc[fm], 0, 0, 0); }

  LA2(0, aA); LB2(0, rbA);
  LA2(1, aB); LB2(1, rbB);
  for (int kt = 0; kt < NK; kt += 2) {
    COMP2(aA, rbA);
    if (kt + 2 < NK) { LA2(kt + 2, aA); LB2(kt + 2, rbA); }
    COMP2(aB, rbB);
    if (kt + 3 < NK) { LA2(kt + 3, aB); LB2(kt + 3, rbB); }
  }

  const float bias = dbias[e * HIDDEN + col];
  const int rowBase = m0 + wr * 128 + ((lane >> 4) * 4);
  #pragma unroll
  for (int fm = 0; fm < 8; ++fm) {
    #pragma unroll
    for (int j = 0; j < 4; ++j) {
      int row = rowBase + fm * 16 + j;
      if (row < n_e) {
        int aidx = list[base + row];
        out[(size_t)aidx * HIDDEN + col] = acc[fm][j] + bias;
      }
    }
  }
}

extern "C" void kernel_launch(void* const* d_in, const int* in_sizes, int n_in,
                              void* d_out, int out_size, void* d_ws, size_t ws_size,
                              hipStream_t stream) {
  const float* t     = (const float*)d_in[0];
  const int*   eidx  = (const int*)d_in[1];
  const float* gup   = (const float*)d_in[2];
  const float* gub   = (const float*)d_in[3];
  const float* dwn   = (const float*)d_in[4];
  const float* dbias = (const float*)d_in[5];
  float* out = (float*)d_out;

  char* ws = (char*)d_ws;
  __hip_bfloat16* u    = (__hip_bfloat16*)ws;
  __hip_bfloat16* abuf = (__hip_bfloat16*)(ws + UBYTES);
  int* meta = (int*)(ws + UBYTES + ABYTES);   // 24 ints
  int* list = meta + 24;                      // 2048 ints

  route_count<<<1, 256, 0, stream>>>(eidx, meta);
  route_scatter<<<NPAIR / 256, 256, 0, stream>>>(eidx, meta, list);
  gather_a<<<NPAIR, 256, 0, stream>>>(t, list, abuf);

  dim3 g1(GUP_ROWS / BN1, MT_MAX, NEXP);   // 45 x 3 x 8
  gemm1_swiglu<<<g1, 512, 0, stream>>>(abuf, gup, gub, meta, u);

  dim3 g2(HIDDEN / BN2, MT_MAX, NEXP);     // 45 x 3 x 8
  gemm2_down<<<g2, 512, 0, stream>>>(u, dwn, dbias, meta, list, out);
}

// Round 5
// 464.885 us; speedup vs baseline: 2.4888x; 2.4888x over previous
//
#include <hip/hip_runtime.h>
#include <hip/hip_bf16.h>

#define HIDDEN   2880
#define INTER    2880
#define NEXP     8
#define GUP_ROWS 5760
#define NPAIR    2048

#define NKT  90              // k-tiles of 32 (both gemms: 2880/32)
#define BM   128
#define BN1  128
#define BN2  64
#define NT   256
#define MT_GRID 16           // worst-case m-tiles per expert; extras exit

#define MAXTILES 24          // sum_e ceil(n_e/128) <= 8 + 2048/128 = 24
#define TILE_BYTES 8192      // one (tile,kt) A-image: 4 kq-planes x 128 rows x 16B
#define IMG_BYTES ((size_t)MAXTILES * NKT * TILE_BYTES)   // ~17.7 MB

using bf16x8 = __attribute__((ext_vector_type(8))) short;
using f32x4  = __attribute__((ext_vector_type(4))) float;

typedef const __attribute__((address_space(1))) unsigned GBuf;
typedef __attribute__((address_space(3))) unsigned LBuf;

__device__ __forceinline__ void gl2lds(const void* g, void* l) {
  __builtin_amdgcn_global_load_lds((GBuf*)g, (LBuf*)l, 16, 0, 0);
}

__device__ __forceinline__ unsigned cvt2bf(float a, float b) {
  union { __hip_bfloat16 h; unsigned short s; } x, y;
  x.h = __float2bfloat16(a);
  y.h = __float2bfloat16(b);
  return (unsigned)x.s | ((unsigned)y.s << 16);
}

__device__ __forceinline__ bf16x8 cvt8(const float4& lo, const float4& hi) {
  union { bf16x8 v; unsigned u[4]; } r;
  r.u[0] = cvt2bf(lo.x, lo.y);
  r.u[1] = cvt2bf(lo.z, lo.w);
  r.u[2] = cvt2bf(hi.x, hi.y);
  r.u[3] = cvt2bf(hi.z, hi.w);
  return r.v;
}

// ---------------- routing ----------------
// meta: [0..7]=counts [8..15]=row offsets [16..23]=cursor [24..31]=tile base
__global__ void route_count(const int* __restrict__ eidx, int* __restrict__ meta) {
  __shared__ int cnt[NEXP];
  int t = threadIdx.x;
  if (t < NEXP) cnt[t] = 0;
  __syncthreads();
  for (int a = t; a < NPAIR; a += 256) atomicAdd(&cnt[eidx[a]], 1);
  __syncthreads();
  if (t == 0) {
    int off = 0, toff = 0;
    for (int e = 0; e < NEXP; ++e) {
      meta[e] = cnt[e];
      meta[8 + e] = off;
      meta[16 + e] = off;
      meta[24 + e] = toff;
      off += cnt[e];
      toff += (cnt[e] + BM - 1) >> 7;
    }
  }
}

__global__ void route_scatter(const int* __restrict__ eidx, int* __restrict__ meta,
                              int* __restrict__ list) {
  int a = blockIdx.x * 256 + threadIdx.x;
  int e = eidx[a];
  int pos = atomicAdd(&meta[16 + e], 1);
  list[pos] = a;   // a = token*4 + slot
}

// ---------------- gather A rows -> bf16 tiled LDS-image ----------------
__global__ void gather_a(const float* __restrict__ t, const int* __restrict__ eidx,
                         const int* __restrict__ meta, const int* __restrict__ list,
                         char* __restrict__ atile) {
  const int i = blockIdx.x;             // packed pair slot
  const int a = list[i];
  const int e = eidx[a];
  const int r = i - meta[8 + e];        // expert-local row
  const int tile = meta[24 + e] + (r >> 7);
  const int row = r & (BM - 1);
  const float* src = t + (size_t)(a >> 2) * HIDDEN;
  for (int ch = threadIdx.x; ch < HIDDEN / 8; ch += 256) {
    int kt = ch >> 2, kq = ch & 3;
    const float4* s = (const float4*)(src + ch * 8);
    float4 v0 = s[0], v1 = s[1];
    uint4 w;
    w.x = cvt2bf(v0.x, v0.y); w.y = cvt2bf(v0.z, v0.w);
    w.z = cvt2bf(v1.x, v1.y); w.w = cvt2bf(v1.z, v1.w);
    *(uint4*)(atile + ((size_t)(tile * NKT + kt)) * TILE_BYTES + kq * 2048 + row * 16) = w;
  }
}

// ---------------- GEMM1: h = A @ gup^T + bias ; u = swiglu(h) -> utile ----------------
// LDS: A 2x8KB (image copy), B 2x16KB kq-plane f32. 4 waves, wave tile 64x64.
__global__ __launch_bounds__(NT, 3)
void gemm1_swiglu(const char* __restrict__ atile,
                  const float* __restrict__ gup,
                  const float* __restrict__ gub,
                  const int* __restrict__ meta,
                  char* __restrict__ utile)
{
  const int e = blockIdx.z, mt = blockIdx.y, nt = blockIdx.x;
  const int n_e = meta[e];
  const int m0 = mt * BM;
  if (m0 >= n_e) return;
  const int tile = meta[24 + e] + mt;

  __shared__ __align__(16) char lds[2 * 8192 + 2 * 16384];
  char* ldsA = lds;
  char* ldsB = lds + 2 * 8192;

  const int tid = threadIdx.x, lane = tid & 63, wid = tid >> 6;
  const int wm = wid >> 1, wn = wid & 1;

  auto STAGE = [&](int kt, int buf) {
    const char* as = atile + ((size_t)(tile * NKT + kt)) * TILE_BYTES;
    char* ad = ldsA + buf * 8192;
    #pragma unroll
    for (int j = 0; j < 2; ++j) {
      int c = wid * 2 + j;
      gl2lds(as + c * 1024 + lane * 16, ad + c * 1024);
    }
    char* bd = ldsB + buf * 16384;
    #pragma unroll
    for (int j = 0; j < 4; ++j) {
      int c = wid * 4 + j;
      int col = nt * BN1 + (c & 3) * 32 + (lane >> 1);
      const char* bs = (const char*)gup +
          (((size_t)(e * GUP_ROWS + col) * HIDDEN + kt * 32 + (c >> 2) * 8) << 2) +
          (lane & 1) * 16;
      gl2lds(bs, bd + c * 1024);
    }
  };

  f32x4 acc[4][4];
  #pragma unroll
  for (int fm = 0; fm < 4; ++fm)
    #pragma unroll
    for (int fn = 0; fn < 4; ++fn)
      acc[fm][fn] = f32x4{0.f, 0.f, 0.f, 0.f};

  auto COMP = [&](int buf) {
    const char* ab = ldsA + buf * 8192 + (lane >> 4) * 2048 + (wm * 64 + (lane & 15)) * 16;
    const char* bb = ldsB + buf * 16384 + (lane >> 4) * 4096 + (wn * 64 + (lane & 15)) * 32;
    bf16x8 af[4], bf[4];
    #pragma unroll
    for (int fm = 0; fm < 4; ++fm) af[fm] = *(const bf16x8*)(ab + fm * 256);
    #pragma unroll
    for (int fn = 0; fn < 4; ++fn) {
      float4 lo = *(const float4*)(bb + fn * 512);
      float4 hi = *(const float4*)(bb + fn * 512 + 16);
      bf[fn] = cvt8(lo, hi);
    }
    #pragma unroll
    for (int fm = 0; fm < 4; ++fm)
      #pragma unroll
      for (int fn = 0; fn < 4; ++fn)
        acc[fm][fn] = __builtin_amdgcn_mfma_f32_16x16x32_bf16(af[fm], bf[fn], acc[fm][fn], 0, 0, 0);
  };

  STAGE(0, 0);
  __syncthreads();
  for (int kt = 0; kt < NKT; ++kt) {
    if (kt + 1 < NKT) STAGE(kt + 1, (kt + 1) & 1);
    COMP(kt & 1);
    __syncthreads();
  }

  // epilogue: +bias, swiglu (even col = glu, odd = lin), write u into tiled image
  #pragma unroll
  for (int fm = 0; fm < 4; ++fm) {
    #pragma unroll
    for (int fn = 0; fn < 4; ++fn) {
      const int colg = nt * BN1 + wn * 64 + fn * 16 + (lane & 15);
      const float bias = gub[e * GUP_ROWS + colg];
      #pragma unroll
      for (int j = 0; j < 4; ++j) {
        float h = acc[fm][fn][j] + bias;
        float other = __shfl_xor(h, 1, 64);
        int rowin = wm * 64 + fm * 16 + (lane >> 4) * 4 + j;
        if (!(lane & 1) && (m0 + rowin) < n_e) {
          float xg = fminf(h, 7.0f);
          float xl = fminf(fmaxf(other, -7.0f), 7.0f);
          float og = xg / (1.0f + __expf(-1.702f * xg));
          float uv = og * (xl + 1.0f);
          int uc = colg >> 1;   // 0..2879
          *(__hip_bfloat16*)(utile +
              ((size_t)(tile * NKT + (uc >> 5))) * TILE_BYTES +
              ((uc >> 3) & 3) * 2048 + rowin * 16 + (uc & 7) * 2) = __float2bfloat16(uv);
        }
      }
    }
  }
}

// ---------------- GEMM2: y = u @ dwn^T + dbias, scatter ----------------
// LDS: A 2x8KB (utile copy), B 2x8KB kq-plane f32. 4 waves, wave tile 64x32.
__global__ __launch_bounds__(NT, 3)
void gemm2_down(const char* __restrict__ utile,
                const float* __restrict__ dwn,
                const float* __restrict__ dbias,
                const int* __restrict__ meta,
                const int* __restrict__ list,
                float* __restrict__ out)
{
  const int e = blockIdx.z, mt = blockIdx.y, nt = blockIdx.x;
  const int n_e = meta[e];
  const int m0 = mt * BM;
  if (m0 >= n_e) return;
  const int base = meta[8 + e];
  const int tile = meta[24 + e] + mt;

  __shared__ __align__(16) char lds[2 * 8192 + 2 * 8192];
  char* ldsA = lds;
  char* ldsB = lds + 2 * 8192;

  const int tid = threadIdx.x, lane = tid & 63, wid = tid >> 6;
  const int wm = wid >> 1, wn = wid & 1;

  auto STAGE = [&](int kt, int buf) {
    const char* as = utile + ((size_t)(tile * NKT + kt)) * TILE_BYTES;
    char* ad = ldsA + buf * 8192;
    #pragma unroll
    for (int j = 0; j < 2; ++j) {
      int c = wid * 2 + j;
      gl2lds(as + c * 1024 + lane * 16, ad + c * 1024);
    }
    char* bd = ldsB + buf * 8192;
    #pragma unroll
    for (int j = 0; j < 2; ++j) {
      int c = wid * 2 + j;
      int col = nt * BN2 + (c & 1) * 32 + (lane >> 1);
      const char* bs = (const char*)dwn +
          (((size_t)(e * HIDDEN + col) * INTER + kt * 32 + (c >> 1) * 8) << 2) +
          (lane & 1) * 16;
      gl2lds(bs, bd + c * 1024);
    }
  };

  f32x4 acc[4][2];
  #pragma unroll
  for (int fm = 0; fm < 4; ++fm)
    #pragma unroll
    for (int fn = 0; fn < 2; ++fn)
      acc[fm][fn] = f32x4{0.f, 0.f, 0.f, 0.f};

  auto COMP = [&](int buf) {
    const char* ab = ldsA + buf * 8192 + (lane >> 4) * 2048 + (wm * 64 + (lane & 15)) * 16;
    const char* bb = ldsB + buf * 8192 + (lane >> 4) * 2048 + (wn * 32 + (lane & 15)) * 32;
    bf16x8 af[4], bf[2];
    #pragma unroll
    for (int fm = 0; fm < 4; ++fm) af[fm] = *(const bf16x8*)(ab + fm * 256);
    #pragma unroll
    for (int fn = 0; fn < 2; ++fn) {
      float4 lo = *(const float4*)(bb + fn * 512);
      float4 hi = *(const float4*)(bb + fn * 512 + 16);
      bf[fn] = cvt8(lo, hi);
    }
    #pragma unroll
    for (int fm = 0; fm < 4; ++fm)
      #pragma unroll
      for (int fn = 0; fn < 2; ++fn)
        acc[fm][fn] = __builtin_amdgcn_mfma_f32_16x16x32_bf16(af[fm], bf[fn], acc[fm][fn], 0, 0, 0);
  };

  STAGE(0, 0);
  __syncthreads();
  for (int kt = 0; kt < NKT; ++kt) {
    if (kt + 1 < NKT) STAGE(kt + 1, (kt + 1) & 1);
    COMP(kt & 1);
    __syncthreads();
  }

  #pragma unroll
  for (int fm = 0; fm < 4; ++fm) {
    #pragma unroll
    for (int j = 0; j < 4; ++j) {
      int rL = m0 + wm * 64 + fm * 16 + (lane >> 4) * 4 + j;
      int aidx = (rL < n_e) ? list[base + rL] : -1;
      #pragma unroll
      for (int fn = 0; fn < 2; ++fn) {
        int col = nt * BN2 + wn * 32 + fn * 16 + (lane & 15);
        if (aidx >= 0)
          out[(size_t)aidx * HIDDEN + col] = acc[fm][fn][j] + dbias[e * HIDDEN + col];
      }
    }
  }
}

extern "C" void kernel_launch(void* const* d_in, const int* in_sizes, int n_in,
                              void* d_out, int out_size, void* d_ws, size_t ws_size,
                              hipStream_t stream) {
  const float* t     = (const float*)d_in[0];
  const int*   eidx  = (const int*)d_in[1];
  const float* gup   = (const float*)d_in[2];
  const float* gub   = (const float*)d_in[3];
  const float* dwn   = (const float*)d_in[4];
  const float* dbias = (const float*)d_in[5];
  float* out = (float*)d_out;

  char* ws = (char*)d_ws;
  char* atile = ws;                       // IMG_BYTES
  char* utile = ws + IMG_BYTES;           // IMG_BYTES
  int* meta = (int*)(ws + 2 * IMG_BYTES); // 32 ints
  int* list = meta + 32;                  // 2048 ints

  route_count<<<1, 256, 0, stream>>>(eidx, meta);
  route_scatter<<<NPAIR / 256, 256, 0, stream>>>(eidx, meta, list);
  gather_a<<<NPAIR, 256, 0, stream>>>(t, eidx, meta, list, atile);

  dim3 g1(GUP_ROWS / BN1, MT_GRID, NEXP);   // 45 x 16 x 8
  gemm1_swiglu<<<g1, NT, 0, stream>>>(atile, gup, gub, meta, utile);

  dim3 g2(HIDDEN / BN2, MT_GRID, NEXP);     // 45 x 16 x 8
  gemm2_down<<<g2, NT, 0, stream>>>(utile, dwn, dbias, meta, list, out);
}